// Round 6
// baseline (1436.929 us; speedup 1.0000x reference)
//
#include <hip/hip_runtime.h>
#include <math.h>

#define NN 12288
#define DD 128
#define EPSF 1e-7f
#define MAXNORM (1.0f - 1e-3f)

typedef __attribute__((ext_vector_type(8))) short short8_t;
typedef __attribute__((ext_vector_type(4))) float float4_t;
typedef unsigned short ushort_t;

__device__ __forceinline__ unsigned short f2bf(float f) {
    unsigned int u = __builtin_bit_cast(unsigned int, f);
    unsigned int r = u + 0x7FFFu + ((u >> 16) & 1u);
    return (unsigned short)(r >> 16);
}

// ---------------- Kernel 1: per-row prep ----------------
__global__ __launch_bounds__(128) void prep_kernel(
    const float* __restrict__ x, const float* __restrict__ a,
    ushort_t* __restrict__ xtb,
    float* __restrict__ wh1, float* __restrict__ wh2)
{
    const int r = blockIdx.x;
    const int t = threadIdx.x;
    const float xv = x[r * DD + t];
    const float a1 = a[t];
    const float a2 = a[DD + t];
    float s0 = xv * xv, s1 = xv * a1, s2 = xv * a2;
    #pragma unroll
    for (int o = 32; o > 0; o >>= 1) {
        s0 += __shfl_xor(s0, o);
        s1 += __shfl_xor(s1, o);
        s2 += __shfl_xor(s2, o);
    }
    __shared__ float red[6];
    const int w = t >> 6;
    if ((t & 63) == 0) { red[w * 3 + 0] = s0; red[w * 3 + 1] = s1; red[w * 3 + 2] = s2; }
    __syncthreads();
    const float sumsq = red[0] + red[3];
    const float d1    = red[1] + red[4];
    const float d2    = red[2] + red[5];
    const float nraw  = sqrtf(sumsq);
    const float nrm   = fminf(fmaxf(nraw, EPSF), 1.0f - EPSF);
    const float scale = atanhf(nrm) / nrm;
    xtb[(size_t)r * DD + t] = f2bf(xv * scale);
    if (t == 0) {
        wh1[r] = scale * d1;
        wh2[r] = scale * d2;
    }
}

// ---------------- Kernel 2: build xtB in MFMA-B-fragment-linear layout ----
// chunk C (32 j), dt: 1 KB block; element (lane, e) = xt[C*32+(lane>>4)*8+e][dt*16+(lane&15)]
__global__ __launch_bounds__(256) void swizzle_kernel(
    const ushort_t* __restrict__ xtb, ushort_t* __restrict__ xtB)
{
    __shared__ ushort_t raw[32 * 136];
    const int C = blockIdx.x;
    const int t = threadIdx.x;
    #pragma unroll
    for (int p = 0; p < 2; ++p) {
        const int idx = p * 256 + t;
        const int j = idx >> 4, cell = idx & 15;
        const uint4 v = *(const uint4*)(xtb + (size_t)(C * 32 + j) * DD + cell * 8);
        *(uint4*)&raw[j * 136 + cell * 8] = v;
    }
    __syncthreads();
    #pragma unroll
    for (int p = 0; p < 2; ++p) {
        const int oc = p * 256 + t;       // 0..511 = dt*64 + lane
        const int dt = oc >> 6;
        const int l6 = oc & 63;
        const int l15 = l6 & 15, q = l6 >> 4;
        short8_t v;
        #pragma unroll
        for (int e = 0; e < 8; ++e)
            v[e] = (short)raw[(q * 8 + e) * 136 + dt * 16 + l15];
        *(short8_t*)(xtB + (size_t)C * 4096 + oc * 8) = v;
    }
}

// ---------------- Kernel 3: B-resident-in-LDS MFMA attention ----------------
// grid (32, S). Block: 4 waves, i-chunk = 384 rows (6 i-tiles of 16 per wave),
// j-window = NN/S cols processed in 512-col sub-windows. B staged to LDS once
// per sub-window; main loop has NO barriers and a single VMEM stream (adj+wh2)
// software-pipelined one 128-j quarter ahead -> clean vmcnt overlap.
__global__ __launch_bounds__(256) void attn_kernel(
    const int* __restrict__ adj,
    const ushort_t* __restrict__ xtB,
    const float* __restrict__ wh1, const float* __restrict__ wh2,
    float* __restrict__ pout, float* __restrict__ plsum, int S)
{
    __shared__ __align__(16) ushort_t B_lds[512 * 128];   // 128 KB

    const int t = threadIdx.x;
    const int w = t >> 6, lane = t & 63;
    const int l15 = lane & 15, quad = lane >> 4;
    const int s = blockIdx.y;
    const int jwin = NN / S;
    const int nsub = jwin >> 9;
    const int i_chunk = blockIdx.x * 384;

    for (int sub = 0; sub < nsub; ++sub) {
        const int jw = s * jwin + (sub << 9);
        if (sub) __syncthreads();
        // ---- stage B window (128 KB) into LDS, linear copy ----
        {
            const uint4* src = (const uint4*)(xtB + (size_t)(jw >> 5) * 4096);
            uint4* dst = (uint4*)B_lds;
            #pragma unroll
            for (int m = 0; m < 32; ++m) dst[m * 256 + t] = src[m * 256 + t];
        }
        __syncthreads();

        int4   Ab[2][4][2];
        float4 Wb[2][4][2];

        // ---- prologue: prefetch step 0 (it=0, q=0) ----
        {
            const int i0 = i_chunk + w * 16;
            const size_t rb = (size_t)(i0 + l15) * NN + jw + quad * 8;
            const int wb2 = jw + quad * 8;
            #pragma unroll
            for (int kc = 0; kc < 4; ++kc)
                #pragma unroll
                for (int e = 0; e < 2; ++e) {
                    Ab[0][kc][e] = *(const int4*)(adj + rb + kc * 32 + e * 4);
                    Wb[0][kc][e] = *(const float4*)(wh2 + wb2 + kc * 32 + e * 4);
                }
        }

        float4_t acc[8];
        float lsum = 0.0f;
        float wh1i = 0.0f;

        for (int step = 0; step < 24; ++step) {
            const int it = step >> 2, q = step & 3;
            const int cur = step & 1, nxt = cur ^ 1;

            // ---- prefetch step+1 (only VMEM stream in the loop) ----
            {
                const int ns = (step < 23) ? step + 1 : step;
                const int nit = ns >> 2, nq = ns & 3;
                const int i0n = i_chunk + (w + 4 * nit) * 16;
                const size_t rb = (size_t)(i0n + l15) * NN + jw + nq * 128 + quad * 8;
                const int wb2 = jw + nq * 128 + quad * 8;
                #pragma unroll
                for (int kc = 0; kc < 4; ++kc)
                    #pragma unroll
                    for (int e = 0; e < 2; ++e) {
                        Ab[nxt][kc][e] = *(const int4*)(adj + rb + kc * 32 + e * 4);
                        Wb[nxt][kc][e] = *(const float4*)(wh2 + wb2 + kc * 32 + e * 4);
                    }
            }

            const int i0 = i_chunk + (w + 4 * it) * 16;
            if (q == 0) {
                #pragma unroll
                for (int dt = 0; dt < 8; ++dt) acc[dt] = (float4_t)0.0f;
                lsum = 0.0f;
                wh1i = wh1[i0 + l15];
            }

            // ---- process current quarter: p in A-layout + 32 MFMAs ----
            #pragma unroll
            for (int kc = 0; kc < 4; ++kc) {
                short8_t af;
                #pragma unroll
                for (int e = 0; e < 2; ++e) {
                    const int4   A = Ab[cur][kc][e];
                    const float4 W = Wb[cur][kc][e];
                    const float u0 = wh1i + W.x, u1 = wh1i + W.y;
                    const float u2 = wh1i + W.z, u3 = wh1i + W.w;
                    const float p0 = (A.x > 0) ? __expf(fmaxf(u0, 0.2f * u0)) : 0.0f;
                    const float p1 = (A.y > 0) ? __expf(fmaxf(u1, 0.2f * u1)) : 0.0f;
                    const float p2 = (A.z > 0) ? __expf(fmaxf(u2, 0.2f * u2)) : 0.0f;
                    const float p3 = (A.w > 0) ? __expf(fmaxf(u3, 0.2f * u3)) : 0.0f;
                    lsum += (p0 + p1) + (p2 + p3);
                    af[e * 4 + 0] = (short)f2bf(p0);
                    af[e * 4 + 1] = (short)f2bf(p1);
                    af[e * 4 + 2] = (short)f2bf(p2);
                    af[e * 4 + 3] = (short)f2bf(p3);
                }
                const int cb = (q * 4 + kc) * 4096;   // chunk base in shorts (8*512)
                #pragma unroll
                for (int dt = 0; dt < 8; ++dt) {
                    const short8_t Bf = *(const short8_t*)&B_lds[cb + dt * 512 + lane * 8];
                    acc[dt] = __builtin_amdgcn_mfma_f32_16x16x32_bf16(af, Bf, acc[dt], 0, 0, 0);
                }
            }

            // ---- i-tile epilogue ----
            if (q == 3) {
                float v = lsum;
                v += __shfl_xor(v, 16);
                v += __shfl_xor(v, 32);
                if (quad == 0) {
                    float* lp = plsum + (size_t)s * NN + i0 + l15;
                    if (sub == 0) *lp = v; else *lp += v;
                }
                #pragma unroll
                for (int dt = 0; dt < 8; ++dt)
                    #pragma unroll
                    for (int reg = 0; reg < 4; ++reg) {
                        float* op = pout + ((size_t)s * NN + i0 + quad * 4 + reg) * DD
                                    + dt * 16 + l15;
                        if (sub == 0) *op = acc[dt][reg];
                        else         *op += acc[dt][reg];
                    }
            }
        }
    }
}

// ---------------- Kernel 4: combine partials + normalize + expmap0 + proj ----
__global__ __launch_bounds__(128) void reduce_kernel(
    const float* __restrict__ pout, const float* __restrict__ plsum,
    float* __restrict__ out, int S)
{
    const int i = blockIdx.x;
    const int t = threadIdx.x;
    float v = 0.0f;
    for (int s = 0; s < S; ++s) v += pout[((size_t)s * NN + i) * DD + t];
    float ls = 0.0f;
    for (int s = 0; s < S; ++s) ls += plsum[(size_t)s * NN + i];
    v /= ls;
    float ss = v * v;
    #pragma unroll
    for (int o = 1; o < 64; o <<= 1) ss += __shfl_xor(ss, o);
    __shared__ float r2[2];
    if ((t & 63) == 0) r2[t >> 6] = ss;
    __syncthreads();
    const float total = r2[0] + r2[1];
    const float nraw = sqrtf(total);
    const float nv   = fmaxf(nraw, EPSF);
    const float th   = tanhf(nv);
    const float ysc  = th / nv;
    const float nyr  = ysc * nraw;
    const float ny   = fmaxf(nyr, EPSF);
    const float psc  = (ny > MAXNORM) ? (MAXNORM / ny) : 1.0f;
    const float os   = ysc * psc;
    out[(size_t)i * DD + t] = v * os;
}

extern "C" void kernel_launch(void* const* d_in, const int* in_sizes, int n_in,
                              void* d_out, int out_size, void* d_ws, size_t ws_size,
                              hipStream_t stream) {
    const float* x   = (const float*)d_in[0];
    const int*   adj = (const int*)d_in[1];
    const float* a   = (const float*)d_in[2];
    float* out = (float*)d_out;

    // ---- workspace layout ----
    char* ws = (char*)d_ws;
    ushort_t* xtb = (ushort_t*)ws;  ws += (size_t)NN * DD * sizeof(ushort_t);
    ushort_t* xtB = (ushort_t*)ws;  ws += (size_t)NN * DD * sizeof(ushort_t);
    float* wh1 = (float*)ws;        ws += NN * sizeof(float);
    float* wh2 = (float*)ws;        ws += NN * sizeof(float);

    const size_t fixed = (size_t)(ws - (char*)d_ws);
    const size_t perS  = (size_t)NN * DD * sizeof(float) + NN * sizeof(float);
    // S must divide 24 so the j-window is a multiple of 512.
    int S = 1;
    const int cand[7] = {24, 12, 8, 6, 4, 3, 2};
    for (int c = 0; c < 7; ++c) {
        if (fixed + (size_t)cand[c] * perS <= ws_size) { S = cand[c]; break; }
    }
    float* plsum = (float*)ws;      ws += (size_t)S * NN * sizeof(float);
    float* pout  = (float*)ws;

    prep_kernel<<<NN, 128, 0, stream>>>(x, a, xtb, wh1, wh2);
    swizzle_kernel<<<NN / 32, 256, 0, stream>>>(xtb, xtB);
    attn_kernel<<<dim3(NN / 384, S), 256, 0, stream>>>(
        adj, xtB, wh1, wh2, pout, plsum, S);
    reduce_kernel<<<NN, 128, 0, stream>>>(pout, plsum, out, S);
}

// Round 7
// 859.021 us; speedup vs baseline: 1.6728x; 1.6728x over previous
//
#include <hip/hip_runtime.h>
#include <math.h>

#define NN 12288
#define DD 128
#define EPSF 1e-7f
#define MAXNORM (1.0f - 1e-3f)
#define S_SLABS 24

typedef __attribute__((ext_vector_type(8))) short short8_t;
typedef __attribute__((ext_vector_type(4))) float float4_t;
typedef unsigned short ushort_t;

__device__ __forceinline__ unsigned short f2bf(float f) {
    unsigned int u = __builtin_bit_cast(unsigned int, f);
    unsigned int r = u + 0x7FFFu + ((u >> 16) & 1u);
    return (unsigned short)(r >> 16);
}

// ---------------- Kernel 1: per-row prep ----------------
__global__ __launch_bounds__(128) void prep_kernel(
    const float* __restrict__ x, const float* __restrict__ a,
    ushort_t* __restrict__ xtb,
    float* __restrict__ wh1, float* __restrict__ wh2)
{
    const int r = blockIdx.x;
    const int t = threadIdx.x;
    const float xv = x[r * DD + t];
    const float a1 = a[t];
    const float a2 = a[DD + t];
    float s0 = xv * xv, s1 = xv * a1, s2 = xv * a2;
    #pragma unroll
    for (int o = 32; o > 0; o >>= 1) {
        s0 += __shfl_xor(s0, o);
        s1 += __shfl_xor(s1, o);
        s2 += __shfl_xor(s2, o);
    }
    __shared__ float red[6];
    const int w = t >> 6;
    if ((t & 63) == 0) { red[w * 3 + 0] = s0; red[w * 3 + 1] = s1; red[w * 3 + 2] = s2; }
    __syncthreads();
    const float sumsq = red[0] + red[3];
    const float d1    = red[1] + red[4];
    const float d2    = red[2] + red[5];
    const float nraw  = sqrtf(sumsq);
    const float nrm   = fminf(fmaxf(nraw, EPSF), 1.0f - EPSF);
    const float scale = atanhf(nrm) / nrm;
    xtb[(size_t)r * DD + t] = f2bf(xv * scale);
    if (t == 0) {
        wh1[r] = scale * d1;
        wh2[r] = scale * d2;
    }
}

// ---------------- Kernel 2: build xtB in MFMA-B-fragment-linear layout ----
// chunk C (32 j), dt: 1 KB block; element (lane, e) = xt[C*32+(lane>>4)*8+e][dt*16+(lane&15)]
__global__ __launch_bounds__(256) void swizzle_kernel(
    const ushort_t* __restrict__ xtb, ushort_t* __restrict__ xtB)
{
    __shared__ ushort_t raw[32 * 136];
    const int C = blockIdx.x;
    const int t = threadIdx.x;
    #pragma unroll
    for (int p = 0; p < 2; ++p) {
        const int idx = p * 256 + t;
        const int j = idx >> 4, cell = idx & 15;
        const uint4 v = *(const uint4*)(xtb + (size_t)(C * 32 + j) * DD + cell * 8);
        *(uint4*)&raw[j * 136 + cell * 8] = v;
    }
    __syncthreads();
    #pragma unroll
    for (int p = 0; p < 2; ++p) {
        const int oc = p * 256 + t;       // 0..511 = dt*64 + lane
        const int dt = oc >> 6;
        const int l6 = oc & 63;
        const int l15 = l6 & 15, q = l6 >> 4;
        short8_t v;
        #pragma unroll
        for (int e = 0; e < 8; ++e)
            v[e] = (short)raw[(q * 8 + e) * 136 + dt * 16 + l15];
        *(short8_t*)(xtB + (size_t)C * 4096 + oc * 8) = v;
    }
}

// ---------------- Kernel 3: slab-resident MFMA attention ----------------
// grid (48, 24). Block: 4 waves, owns rows [bx*256, +256) x j-slab [s*512, +512).
// B (128 KB) + wh2 (2 KB) staged to LDS ONCE (single barrier). Main loop:
// adj is the ONLY global stream, prefetch distance 2, named buffers (no
// dynamic indexing -> no scratch), fully unrolled schedule.
__global__ __launch_bounds__(256, 1) void attn_kernel(
    const int* __restrict__ adj,
    const ushort_t* __restrict__ xtB,
    const float* __restrict__ wh1, const float* __restrict__ wh2,
    float* __restrict__ pout, float* __restrict__ plsum)
{
    __shared__ __align__(16) ushort_t B_lds[512 * DD];   // 128 KB
    __shared__ __align__(16) float wh2_lds[512];         //   2 KB

    const int t = threadIdx.x;
    const int w = t >> 6, lane = t & 63;
    const int l15 = lane & 15, quad = lane >> 4;
    const int s = blockIdx.y;                // j-slab
    const int jcol0 = s * 512;
    const int rowbase = blockIdx.x * 256 + w * 64;   // wave's 64 rows

    // ---- stage B + wh2 window ----
    {
        const uint4* src = (const uint4*)(xtB + (size_t)(jcol0 >> 5) * 4096);
        uint4* dst = (uint4*)B_lds;
        #pragma unroll
        for (int m = 0; m < 32; ++m) dst[m * 256 + t] = src[m * 256 + t];
        wh2_lds[t]       = wh2[jcol0 + t];
        wh2_lds[256 + t] = wh2[jcol0 + 256 + t];
    }

    // ---- preload wh1 for this wave's 4 i-tiles (keeps vmcnt queue clean) ----
    float wh1r[4];
    #pragma unroll
    for (int it = 0; it < 4; ++it) wh1r[it] = wh1[rowbase + it * 16 + l15];

    __syncthreads();

    const int* adj_lane = adj + (size_t)(rowbase + l15) * NN + jcol0 + quad * 8;

    float4_t acc[8];
    float lsum = 0.0f;
    int4 A0[8], A1[8], A2[8];

    auto load_step = [&](int st, int4 (&A)[8]) {
        const int it = st >> 2, jh = st & 3;
        const int* bp = adj_lane + (size_t)it * 16 * NN + jh * 128;
        #pragma unroll
        for (int kc = 0; kc < 4; ++kc) {
            A[kc * 2 + 0] = *(const int4*)(bp + kc * 32);
            A[kc * 2 + 1] = *(const int4*)(bp + kc * 32 + 4);
        }
    };

    auto process = [&](int st, int4 (&A)[8]) {
        const int it = st >> 2, jh = st & 3;
        if (jh == 0) {
            #pragma unroll
            for (int dt = 0; dt < 8; ++dt) acc[dt] = (float4_t)0.0f;
            lsum = 0.0f;
        }
        const float wh1i = wh1r[it];
        #pragma unroll
        for (int kc = 0; kc < 4; ++kc) {
            const int wbase = jh * 128 + kc * 32 + quad * 8;
            const float4 Wa = *(const float4*)&wh2_lds[wbase];
            const float4 Wb = *(const float4*)&wh2_lds[wbase + 4];
            const int4 Aa = A[kc * 2 + 0], Ac = A[kc * 2 + 1];
            const float u0 = wh1i + Wa.x, u1 = wh1i + Wa.y;
            const float u2 = wh1i + Wa.z, u3 = wh1i + Wa.w;
            const float u4 = wh1i + Wb.x, u5 = wh1i + Wb.y;
            const float u6 = wh1i + Wb.z, u7 = wh1i + Wb.w;
            const float p0 = (Aa.x > 0) ? __expf(fmaxf(u0, 0.2f * u0)) : 0.0f;
            const float p1 = (Aa.y > 0) ? __expf(fmaxf(u1, 0.2f * u1)) : 0.0f;
            const float p2 = (Aa.z > 0) ? __expf(fmaxf(u2, 0.2f * u2)) : 0.0f;
            const float p3 = (Aa.w > 0) ? __expf(fmaxf(u3, 0.2f * u3)) : 0.0f;
            const float p4 = (Ac.x > 0) ? __expf(fmaxf(u4, 0.2f * u4)) : 0.0f;
            const float p5 = (Ac.y > 0) ? __expf(fmaxf(u5, 0.2f * u5)) : 0.0f;
            const float p6 = (Ac.z > 0) ? __expf(fmaxf(u6, 0.2f * u6)) : 0.0f;
            const float p7 = (Ac.w > 0) ? __expf(fmaxf(u7, 0.2f * u7)) : 0.0f;
            lsum += ((p0 + p1) + (p2 + p3)) + ((p4 + p5) + (p6 + p7));
            short8_t af;
            af[0] = (short)f2bf(p0); af[1] = (short)f2bf(p1);
            af[2] = (short)f2bf(p2); af[3] = (short)f2bf(p3);
            af[4] = (short)f2bf(p4); af[5] = (short)f2bf(p5);
            af[6] = (short)f2bf(p6); af[7] = (short)f2bf(p7);
            const int cb = (jh * 4 + kc) * 4096;
            #pragma unroll
            for (int dt = 0; dt < 8; ++dt) {
                const short8_t Bf = *(const short8_t*)&B_lds[cb + dt * 512 + lane * 8];
                acc[dt] = __builtin_amdgcn_mfma_f32_16x16x32_bf16(af, Bf, acc[dt], 0, 0, 0);
            }
        }
        if (jh == 3) {
            float v = lsum;
            v += __shfl_xor(v, 16);
            v += __shfl_xor(v, 32);
            const int row0 = rowbase + it * 16;
            if (quad == 0) plsum[(size_t)s * NN + row0 + l15] = v;
            #pragma unroll
            for (int dt = 0; dt < 8; ++dt)
                #pragma unroll
                for (int reg = 0; reg < 4; ++reg)
                    pout[((size_t)s * NN + row0 + quad * 4 + reg) * DD + dt * 16 + l15]
                        = acc[dt][reg];
        }
    };

    // ---- fully unrolled 16-step schedule, prefetch distance 2 ----
    load_step(0, A0);
    load_step(1, A1);
    #pragma unroll
    for (int st = 0; st < 16; ++st) {
        if (st + 2 < 16) {
            const int m2 = (st + 2) % 3;
            if (m2 == 0)      load_step(st + 2, A0);
            else if (m2 == 1) load_step(st + 2, A1);
            else              load_step(st + 2, A2);
        }
        const int m = st % 3;
        if (m == 0)      process(st, A0);
        else if (m == 1) process(st, A1);
        else             process(st, A2);
    }
}

// ---------------- Kernel 4: combine partials + normalize + expmap0 + proj ----
__global__ __launch_bounds__(128) void reduce_kernel(
    const float* __restrict__ pout, const float* __restrict__ plsum,
    float* __restrict__ out)
{
    const int i = blockIdx.x;
    const int t = threadIdx.x;
    float v = 0.0f;
    for (int s = 0; s < S_SLABS; ++s) v += pout[((size_t)s * NN + i) * DD + t];
    float ls = 0.0f;
    for (int s = 0; s < S_SLABS; ++s) ls += plsum[(size_t)s * NN + i];
    v /= ls;
    float ss = v * v;
    #pragma unroll
    for (int o = 1; o < 64; o <<= 1) ss += __shfl_xor(ss, o);
    __shared__ float r2[2];
    if ((t & 63) == 0) r2[t >> 6] = ss;
    __syncthreads();
    const float total = r2[0] + r2[1];
    const float nraw = sqrtf(total);
    const float nv   = fmaxf(nraw, EPSF);
    const float th   = tanhf(nv);
    const float ysc  = th / nv;
    const float nyr  = ysc * nraw;
    const float ny   = fmaxf(nyr, EPSF);
    const float psc  = (ny > MAXNORM) ? (MAXNORM / ny) : 1.0f;
    const float os   = ysc * psc;
    out[(size_t)i * DD + t] = v * os;
}

extern "C" void kernel_launch(void* const* d_in, const int* in_sizes, int n_in,
                              void* d_out, int out_size, void* d_ws, size_t ws_size,
                              hipStream_t stream) {
    const float* x   = (const float*)d_in[0];
    const int*   adj = (const int*)d_in[1];
    const float* a   = (const float*)d_in[2];
    float* out = (float*)d_out;

    // ---- workspace layout (~160 MB total; ws is ~2.4 GB) ----
    char* ws = (char*)d_ws;
    ushort_t* xtb = (ushort_t*)ws;  ws += (size_t)NN * DD * sizeof(ushort_t);
    ushort_t* xtB = (ushort_t*)ws;  ws += (size_t)NN * DD * sizeof(ushort_t);
    float* wh1 = (float*)ws;        ws += NN * sizeof(float);
    float* wh2 = (float*)ws;        ws += NN * sizeof(float);
    float* plsum = (float*)ws;      ws += (size_t)S_SLABS * NN * sizeof(float);
    float* pout  = (float*)ws;

    prep_kernel<<<NN, 128, 0, stream>>>(x, a, xtb, wh1, wh2);
    swizzle_kernel<<<NN / 32, 256, 0, stream>>>(xtb, xtB);
    attn_kernel<<<dim3(NN / 256, S_SLABS), 256, 0, stream>>>(
        adj, xtB, wh1, wh2, pout, plsum);
    reduce_kernel<<<NN, 128, 0, stream>>>(pout, plsum, out);
}